// Round 13
// baseline (165.773 us; speedup 1.0000x reference)
//
#include <hip/hip_runtime.h>
#include <math.h>

#define D_MODEL 1024
#define N_HEADS 16
#define HEAD_DIM 64
#define BATCH 2
#define SEQ 2048
#define WIN_L 127
#define WIN_R 128

typedef float f32x4 __attribute__((ext_vector_type(4)));
typedef __bf16 bf16x8 __attribute__((ext_vector_type(8)));
typedef unsigned short ushort8_t __attribute__((ext_vector_type(8)));

typedef const __attribute__((address_space(1))) void* gptr_t;
typedef __attribute__((address_space(3))) void* lptr_t;

__device__ __forceinline__ unsigned short f2bf(float v) {
    unsigned u = __float_as_uint(v);
    unsigned r = (u + 0x7FFF + ((u >> 16) & 1)) >> 16;   // RNE
    return (unsigned short)r;
}

// ---------------------------------------------------------------------------
// fp32 -> bf16 for all three inputs + RoPE cos/sin table, one launch.
// Table: ctab[t*32+f] = (cos(t*invf[f]), sin(t*invf[f])), 2048x32 float2=512KB.
// ---------------------------------------------------------------------------
#define NX_ELEM (4096 * 1024)
#define NW_ELEM (3072 * 1024)
#define NO_ELEM (1024 * 1024)
#define NTOT_ELEM (NX_ELEM + NW_ELEM + NO_ELEM)
#define TAB_ELEM (SEQ * 32)                      // 65536 float2 entries

__global__ __launch_bounds__(256)
void cvt_all(const float* __restrict__ x, const float* __restrict__ wq,
             const float* __restrict__ wo, unsigned short* __restrict__ xb,
             unsigned short* __restrict__ wqb, unsigned short* __restrict__ wob,
             float2* __restrict__ ctab)
{
    int i = (blockIdx.x * 256 + threadIdx.x) * 4;
    if (i < NTOT_ELEM) {
        const float* src;
        unsigned short* dst;
        int off;
        if (i < NX_ELEM)                 { src = x;  dst = xb;  off = i; }
        else if (i < NX_ELEM + NW_ELEM)  { src = wq; dst = wqb; off = i - NX_ELEM; }
        else                             { src = wo; dst = wob; off = i - NX_ELEM - NW_ELEM; }
        float4 f = *(const float4*)(src + off);
        ushort4 o;
        o.x = f2bf(f.x); o.y = f2bf(f.y); o.z = f2bf(f.z); o.w = f2bf(f.w);
        *(ushort4*)(dst + off) = o;
    } else {
        int e0 = i - NTOT_ELEM;                  // 0..TAB_ELEM-4, step 4
#pragma unroll
        for (int e = 0; e < 4; ++e) {
            const int idx = e0 + e;
            const int t = idx >> 5;
            const int f = idx & 31;
            // inv_freq[f] = 10000^(-f/32) = 2^(-f*log2(10000)/32)
            const float invf = exp2f(-(float)f * 0.41524101186092f);
            const float ang = (float)t * invf;
            ctab[idx] = make_float2(cosf(ang), sinf(ang));
        }
    }
}

// ---------------------------------------------------------------------------
// QKV GEMM (NT) with fused RoPE + layout epilogue.
// R12: T3-minimum 2-phase pipeline. The old loop was 1-phase (barrier ->
// STAGE(cur) -> barrier -> compute(cur)): loads issued then IMMEDIATELY
// drained by the next barrier with zero intervening work (m233: the
// stage+vmcnt+barrier IS the critical path in such structures — which is
// also why R11's swizzle was null at total level per m252's regime gate).
// New loop ping-pongs the existing two BK=32 panel pairs (zero extra LDS):
//   barrier -> STAGE(other, next panel) -> compute(cur)
// Each panel's 4 loads/thread now fly across a full 16-MFMA + 8-ds_read
// phase before their drain. Same barrier count. Race trace: a buffer
// restaged at iter p was last read at iter p-1, separated by one barrier;
// loads issued at p drain at p+1's barrier (compiler vmcnt(0) before
// s_barrier). T2 swizzle kept (conflicts may surface now staging overlaps).
// ---------------------------------------------------------------------------
#define QKV_STAGE(AB, BB, KK)                                                    \
    _Pragma("unroll")                                                            \
    for (int l = 0; l < 2; ++l) {                                                \
        const int r = l * 64 + wave * 16 + srow;                                 \
        __builtin_amdgcn_global_load_lds(                                        \
            (gptr_t)(A + (size_t)(m0 + r) * K + (KK) + scolg),                   \
            (lptr_t)&AB[r * 32 + scol], 16, 0, 0);                               \
        __builtin_amdgcn_global_load_lds(                                        \
            (gptr_t)(B + (size_t)(n0 + r) * K + (KK) + scolg),                   \
            (lptr_t)&BB[r * 32 + scol], 16, 0, 0);                               \
    }

#define QKV_COMPUTE(AP, BP)                                                      \
    {                                                                            \
        bf16x8 af[4], bf[4];                                                     \
        _Pragma("unroll")                                                        \
        for (int i = 0; i < 4; ++i)                                              \
            af[i] = *(const bf16x8*)&AP[(wm + i * 16 + l16) * 32 + cswz];        \
        _Pragma("unroll")                                                        \
        for (int j = 0; j < 4; ++j)                                              \
            bf[j] = *(const bf16x8*)&BP[(wn + j * 16 + l16) * 32 + cswz];        \
        _Pragma("unroll")                                                        \
        for (int i = 0; i < 4; ++i)                                              \
            _Pragma("unroll")                                                    \
            for (int j = 0; j < 4; ++j)                                          \
                acc[i][j] = __builtin_amdgcn_mfma_f32_16x16x32_bf16(             \
                    af[i], bf[j], acc[i][j], 0, 0, 0);                           \
    }

__global__ __launch_bounds__(256, 3)
void gemm_qkv(const unsigned short* __restrict__ A,
              const unsigned short* __restrict__ B,
              unsigned short* __restrict__ qb,
              unsigned short* __restrict__ kb,
              unsigned short* __restrict__ vbT,
              const float2* __restrict__ ctab,
              int M, int N, int K)
{
    __shared__ __attribute__((aligned(16))) unsigned short U[17408]; // 34.8 KB
    unsigned short* Al0 = U;             // 128*32
    unsigned short* Bl0 = U + 4096;
    unsigned short* Al1 = U + 8192;
    unsigned short* Bl1 = U + 12288;

    const int tid  = threadIdx.x;
    const int wave = tid >> 6;
    const int lane = tid & 63;
    const int m0 = blockIdx.y * 128;
    const int n0 = blockIdx.x * 128;

    const int wm = (wave >> 1) * 64;
    const int wn = (wave & 1) * 64;
    const int quad = lane >> 4;
    const int l16  = lane & 15;

    const int srow  = lane >> 2;                               // 0..15
    const int scol  = (lane & 3) * 8;                          // LDS dest (linear)
    const int scolg = ((lane & 3) ^ ((lane >> 3) & 3)) * 8;    // swizzled global col
    const int cswz  = (quad ^ ((l16 >> 1) & 3)) * 8;           // swizzled read col

    f32x4 acc[4][4] = {};

    QKV_STAGE(Al0, Bl0, 0);
    for (int k0 = 0; k0 < K; k0 += 64) {
        __syncthreads();                       // panel k0 ready in {Al0,Bl0}
        QKV_STAGE(Al1, Bl1, k0 + 32);          // k0+32 < K always (K mult of 64)
        QKV_COMPUTE(Al0, Bl0);
        __syncthreads();                       // panel k0+32 ready in {Al1,Bl1}
        if (k0 + 64 < K) QKV_STAGE(Al0, Bl0, k0 + 64);
        QKV_COMPUTE(Al1, Bl1);
    }

    __syncthreads();   // all waves done reading staging before Tw overwrites

    // ---- epilogue ----
    const int which = (n0 >> 10);   // 0=q 1=k 2=v, uniform per block
    unsigned short* Tw = U + wave * 4352;   // 64*68 per wave

    if (which != 2) {
#pragma unroll
        for (int i = 0; i < 4; ++i) {
            const int tb = (m0 + wm + i * 16 + quad * 4) & 2047;
#pragma unroll
            for (int jp = 0; jp < 2; ++jp)
#pragma unroll
                for (int r = 0; r < 4; ++r) {
                    const float2 cs = ctab[(tb + r) * 32 + jp * 16 + l16];
                    float x1 = acc[i][jp][r], x2 = acc[i][jp + 2][r];
                    acc[i][jp][r]     = x1 * cs.x - x2 * cs.y;
                    acc[i][jp + 2][r] = x2 * cs.x + x1 * cs.y;
                }
        }
#pragma unroll
        for (int i = 0; i < 4; ++i)
#pragma unroll
            for (int j = 0; j < 4; ++j)
#pragma unroll
                for (int r = 0; r < 4; ++r)
                    Tw[(i * 16 + quad * 4 + r) * 68 + j * 16 + l16] = f2bf(acc[i][j][r]);
    } else {
#pragma unroll
        for (int i = 0; i < 4; ++i)
#pragma unroll
            for (int j = 0; j < 4; ++j) {
                ushort4 pv;
                pv.x = f2bf(acc[i][j][0]); pv.y = f2bf(acc[i][j][1]);
                pv.z = f2bf(acc[i][j][2]); pv.w = f2bf(acc[i][j][3]);
                *(ushort4*)&Tw[(j * 16 + l16) * 68 + i * 16 + quad * 4] = pv;
            }
    }

    {
        const int h   = ((n0 + wn) >> 6) & 15;
        const int nb  = (m0 + wm) >> 11;
        const int tw0 = (m0 + wm) & 2047;
        const int lr8 = lane >> 3;          // 0..7
        const int lc8 = (lane & 7) * 8;     // element offset in row
        if (which != 2) {
            unsigned short* dst = (which == 0 ? qb : kb);
            unsigned short* gb = dst + (((size_t)nb * 16 + h) * SEQ + tw0) * 64;
#pragma unroll
            for (int c = 0; c < 8; ++c) {
                const int row = c * 8 + lr8;
                ushort4 lo = *(const ushort4*)&Tw[row * 68 + lc8];
                ushort4 hi = *(const ushort4*)&Tw[row * 68 + lc8 + 4];
                ushort8_t v8 = {lo.x, lo.y, lo.z, lo.w, hi.x, hi.y, hi.z, hi.w};
                *(ushort8_t*)&gb[row * 64 + lc8] = v8;
            }
        } else {
            unsigned short* gb = vbT + ((size_t)nb * 16 + h) * 64 * SEQ + tw0;
#pragma unroll
            for (int c = 0; c < 8; ++c) {
                const int drow = c * 8 + lr8;
                ushort4 lo = *(const ushort4*)&Tw[drow * 68 + lc8];
                ushort4 hi = *(const ushort4*)&Tw[drow * 68 + lc8 + 4];
                ushort8_t v8 = {lo.x, lo.y, lo.z, lo.w, hi.x, hi.y, hi.z, hi.w};
                *(ushort8_t*)&gb[(size_t)drow * SEQ + lc8] = v8;
            }
        }
    }
}

// ---------------------------------------------------------------------------
// Out-projection GEMM (NT), fp32 out + bias. BM=64/BN=64, 4 blocks/CU (R7).
// ---------------------------------------------------------------------------
__global__ __launch_bounds__(256, 4)
void gemm_out(const unsigned short* __restrict__ A,
              const unsigned short* __restrict__ B,
              const float* __restrict__ bias, float* __restrict__ C,
              int M, int N, int K)
{
    __shared__ __attribute__((aligned(16))) unsigned short Al0[64 * 32];
    __shared__ __attribute__((aligned(16))) unsigned short Al1[64 * 32];
    __shared__ __attribute__((aligned(16))) unsigned short Bl0[64 * 32];
    __shared__ __attribute__((aligned(16))) unsigned short Bl1[64 * 32];

    const int tid  = threadIdx.x;
    const int wave = tid >> 6;
    const int lane = tid & 63;
    const int m0 = blockIdx.y * 64;
    const int n0 = blockIdx.x * 64;

    const int wm = (wave >> 1) * 32;
    const int wn = (wave & 1) * 32;
    const int quad = lane >> 4;
    const int l16  = lane & 15;

    const int srow = lane >> 2;
    const int scol = (lane & 3) * 8;

    f32x4 acc[2][2] = {};

    for (int k0 = 0; k0 < K; k0 += 64) {
        __syncthreads();
        {
            const int r = wave * 16 + srow;        // 0..63
            const unsigned short* gA = A + (size_t)(m0 + r) * K + k0 + scol;
            const unsigned short* gB = B + (size_t)(n0 + r) * K + k0 + scol;
            __builtin_amdgcn_global_load_lds((gptr_t)gA,        (lptr_t)&Al0[r * 32 + scol], 16, 0, 0);
            __builtin_amdgcn_global_load_lds((gptr_t)(gA + 32), (lptr_t)&Al1[r * 32 + scol], 16, 0, 0);
            __builtin_amdgcn_global_load_lds((gptr_t)gB,        (lptr_t)&Bl0[r * 32 + scol], 16, 0, 0);
            __builtin_amdgcn_global_load_lds((gptr_t)(gB + 32), (lptr_t)&Bl1[r * 32 + scol], 16, 0, 0);
        }
        __syncthreads();

#pragma unroll
        for (int kh = 0; kh < 2; ++kh) {
            const unsigned short* Ap = kh ? Al1 : Al0;
            const unsigned short* Bp = kh ? Bl1 : Bl0;
            bf16x8 af[2], bf[2];
#pragma unroll
            for (int i = 0; i < 2; ++i)
                af[i] = *(const bf16x8*)&Ap[(wm + i * 16 + l16) * 32 + quad * 8];
#pragma unroll
            for (int j = 0; j < 2; ++j)
                bf[j] = *(const bf16x8*)&Bp[(wn + j * 16 + l16) * 32 + quad * 8];
#pragma unroll
            for (int i = 0; i < 2; ++i)
#pragma unroll
                for (int j = 0; j < 2; ++j)
                    acc[i][j] = __builtin_amdgcn_mfma_f32_16x16x32_bf16(af[i], bf[j], acc[i][j], 0, 0, 0);
        }
    }

#pragma unroll
    for (int i = 0; i < 2; ++i) {
        const int row_base = m0 + wm + i * 16 + quad * 4;
#pragma unroll
        for (int j = 0; j < 2; ++j) {
            const int col = n0 + wn + j * 16 + l16;
            const float bv = bias[col];
#pragma unroll
            for (int r = 0; r < 4; ++r)
                C[(size_t)(row_base + r) * N + col] = acc[i][j][r] + bv;
        }
    }
}

// ---------------------------------------------------------------------------
// Banded MFMA flash attention — swapped-operand (T12-spirit), P in-register.
// R5 (verified R7/R8/R11, passed): S^T = mfma(K, Q); lane owns P for keys
// 8*quad+{0..7} at its own t = tw+l16 == the PV B-fragment directly.
// V staging kept (R3 lesson: d-major V direct from global is a 64-way
// uncoalesced wave access; LDS staging IS the coalescing conversion).
// ---------------------------------------------------------------------------
__global__ __launch_bounds__(256, 3)
void attn_mfma(const unsigned short* __restrict__ qb,
               const unsigned short* __restrict__ kb,
               const unsigned short* __restrict__ vbT,
               unsigned short* __restrict__ attnb)
{
    __shared__ __attribute__((aligned(16))) unsigned short Vl[64 * 328]; // [d][trel]

    const int tid  = threadIdx.x;
    const int w    = tid >> 6;
    const int lane = tid & 63;
    const int quad = lane >> 4;
    const int l16  = lane & 15;

    const int t0 = blockIdx.x * 64;
    const int h  = blockIdx.y;
    const int nB = blockIdx.z;
    const int nh = nB * 16 + h;

    const int klo_b = max(0, t0 - WIN_L) & ~31;     // block stage origin

    // ---- stage V band via async global->LDS (41 KB, ~10 loads/lane) ----
    {
        const unsigned short* vbase = vbT + (size_t)nh * 64 * SEQ;
#pragma unroll
        for (int k = 0; k < 11; ++k) {
            const int s = k * 256 + tid;            // seg index, 16 B each
            if (s < 64 * 41) {
                const int row = s / 41;
                const int seg = s - row * 41;
                const int tsrc = min(klo_b + seg * 8, SEQ - 8);   // finite clamp
                __builtin_amdgcn_global_load_lds(
                    (gptr_t)(vbase + (size_t)row * SEQ + tsrc),
                    (lptr_t)&Vl[s * 8], 16, 0, 0);
            }
        }
    }
    __syncthreads();   // drains all staging loads

    const int tw  = t0 + w * 16;
    const int klo = max(0, tw - WIN_L) & ~31;
    const int khi = min(SEQ, tw + 16 + WIN_R);          // exclusive
    const int nchunk = (khi - klo + 31) >> 5;           // <= 9

    const int tq = tw + l16;                            // this lane's t (col)

    const unsigned short* qrow = qb + ((size_t)nh * SEQ + tq) * 64;
    bf16x8 aq0 = *(const bf16x8*)(qrow + quad * 8);
    bf16x8 aq1 = *(const bf16x8*)(qrow + 32 + quad * 8);

    const unsigned short* kbase = kb + (size_t)nh * SEQ * 64;

    f32x4 oacc[4] = {};
    float sm = 0.f;

    // prologue: K frags for chunk 0 (even/odd key pairs — same as before)
    bf16x8 kA0, kA1, kB0, kB1;
    {
        const int keyA = klo + 2 * l16;
        const unsigned short* kpA = kbase + (size_t)min(keyA, SEQ - 1) * 64;
        const unsigned short* kpB = kbase + (size_t)min(keyA + 1, SEQ - 1) * 64;
        kA0 = *(const bf16x8*)(kpA + quad * 8);
        kA1 = *(const bf16x8*)(kpA + 32 + quad * 8);
        kB0 = *(const bf16x8*)(kpB + quad * 8);
        kB1 = *(const bf16x8*)(kpB + 32 + quad * 8);
    }

    for (int kc = 0; kc < nchunk; ++kc) {
        const int s0 = klo + kc * 32;

        // ---- prefetch chunk kc+1's K frags (in flight through exp/PV) ----
        bf16x8 nA0 = kA0, nA1 = kA1, nB0 = kB0, nB1 = kB1;
        if (kc + 1 < nchunk) {
            const int kyA = s0 + 32 + 2 * l16;
            const unsigned short* kpA = kbase + (size_t)min(kyA, SEQ - 1) * 64;
            const unsigned short* kpB = kbase + (size_t)min(kyA + 1, SEQ - 1) * 64;
            nA0 = *(const bf16x8*)(kpA + quad * 8);
            nA1 = *(const bf16x8*)(kpA + 32 + quad * 8);
            nB0 = *(const bf16x8*)(kpB + quad * 8);
            nB1 = *(const bf16x8*)(kpB + 32 + quad * 8);
        }

        // ---- QK^T swapped: S^T tiles (A = K, B = Q) ----
        f32x4 sa = {0.f, 0.f, 0.f, 0.f};   // even keys: s0 + 8*quad + 2r
        f32x4 sb = {0.f, 0.f, 0.f, 0.f};   // odd  keys: s0 + 8*quad + 2r + 1
        __builtin_amdgcn_s_setprio(1);
        sa = __builtin_amdgcn_mfma_f32_16x16x32_bf16(kA0, aq0, sa, 0, 0, 0);
        sa = __builtin_amdgcn_mfma_f32_16x16x32_bf16(kA1, aq1, sa, 0, 0, 0);
        sb = __builtin_amdgcn_mfma_f32_16x16x32_bf16(kB0, aq0, sb, 0, 0, 0);
        sb = __builtin_amdgcn_mfma_f32_16x16x32_bf16(kB1, aq1, sb, 0, 0, 0);
        __builtin_amdgcn_s_setprio(0);

        // ---- mask + exp + row-sum; P stays in registers ----
        ushort8_t pk;
#pragma unroll
        for (int r = 0; r < 4; ++r) {
            const int ka = s0 + 8 * quad + 2 * r;
            const int kb2 = ka + 1;
            const bool vA = (ka  < khi) && (ka  >= tq - WIN_L) && (ka  <= tq + WIN_R);
            const bool vB = (kb2 < khi) && (kb2 >= tq - WIN_L) && (kb2 <= tq + WIN_R);
            // exp(s/8) = exp2(s * 0.125*log2(e)); folded constant (1 mul)
            float p0 = vA ? exp2f(sa[r] * 0.18033688011f) : 0.f;
            float p1 = vB ? exp2f(sb[r] * 0.18033688011f) : 0.f;
            sm += p0 + p1;
            pk[2 * r]     = f2bf(p0);
            pk[2 * r + 1] = f2bf(p1);
        }
        bf16x8 pf = *(bf16x8*)&pk;   // B-frag: keys 8*quad+0..7, col = tq

        // ---- PV swapped: O^T += mfma(A = V^T from LDS, B = P^T in-reg) ----
        const int rel = s0 - klo_b + quad * 8;
        __builtin_amdgcn_s_setprio(1);
#pragma unroll
        for (int j = 0; j < 4; ++j) {
            bf16x8 vf = *(const bf16x8*)&Vl[(j * 16 + l16) * 328 + rel];
            oacc[j] = __builtin_amdgcn_mfma_f32_16x16x32_bf16(vf, pf, oacc[j], 0, 0, 0);
        }
        __builtin_amdgcn_s_setprio(0);

        kA0 = nA0; kA1 = nA1; kB0 = nB0; kB1 = nB1;
    }

    // ---- normalize: lanes sharing t = l16 are the 4 quads (xor 16, 32) ----
    sm += __shfl_xor(sm, 16, 64);
    sm += __shfl_xor(sm, 32, 64);
    const float inv = 1.0f / sm;

    // ---- store O^T: lane holds d = j*16 + quad*4 + r at row t = tq ----
    unsigned short* orow = attnb + ((size_t)(nB * SEQ + tq)) * D_MODEL + h * 64;
#pragma unroll
    for (int j = 0; j < 4; ++j) {
        ushort4 o4;
        o4.x = f2bf(oacc[j][0] * inv);
        o4.y = f2bf(oacc[j][1] * inv);
        o4.z = f2bf(oacc[j][2] * inv);
        o4.w = f2bf(oacc[j][3] * inv);
        *(ushort4*)&orow[j * 16 + quad * 4] = o4;
    }
}

// ---------------------------------------------------------------------------
extern "C" void kernel_launch(void* const* d_in, const int* in_sizes, int n_in,
                              void* d_out, int out_size, void* d_ws, size_t ws_size,
                              hipStream_t stream)
{
    (void)in_sizes; (void)n_in; (void)out_size; (void)ws_size;
    const float* x     = (const float*)d_in[0];
    const float* w_qkv = (const float*)d_in[1];
    const float* w_out = (const float*)d_in[2];
    const float* b_out = (const float*)d_in[3];
    float* out = (float*)d_out;

    const int M = BATCH * SEQ;                 // 4096

    // ws layout (ushorts), ~42.5 MB total:
    //   qb | kb | vbT | wob | xb | wqb | ctab   (attnb reuses xb after QKV)
    unsigned short* qb  = (unsigned short*)d_ws;
    unsigned short* kb  = qb  + (size_t)4194304;
    unsigned short* vbT = kb  + (size_t)4194304;
    unsigned short* wob = vbT + (size_t)4194304;
    unsigned short* xb  = wob + (size_t)1048576;
    unsigned short* wqb = xb  + (size_t)4194304;
    float2* ctab = (float2*)(wqb + (size_t)4194304);   // 512 KB
    unsigned short* attnb = xb;

    dim3 blk(256);

    // 0) fp32 -> bf16 conversions + RoPE table (single launch)
    cvt_all<<<dim3((NTOT_ELEM + TAB_ELEM * 4) / 4 / 256), blk, 0, stream>>>(
        x, w_qkv, w_out, xb, wqb, wob, ctab);

    // 1) fused QKV projection + RoPE -> qb,kb [n,h,t,64], vbT [n,h,64,t] (bf16)
    gemm_qkv<<<dim3(3 * D_MODEL / 128, M / 128), blk, 0, stream>>>(
        xb, wqb, qb, kb, vbT, ctab, M, 3 * D_MODEL, D_MODEL);

    // 2) banded MFMA attention (swapped-operand, P in-register) -> attnb
    attn_mfma<<<dim3(SEQ / 64, N_HEADS, BATCH), blk, 0, stream>>>(qb, kb, vbT, attnb);

    // 3) out = attn @ w_out^T + b_out   (BM=64/BN=64: grid 16 x 64 = 1024 blocks)
    gemm_out<<<dim3(D_MODEL / 64, M / 64), blk, 0, stream>>>(
        attnb, wob, b_out, out, M, D_MODEL, D_MODEL);
}

// Round 15
// 164.325 us; speedup vs baseline: 1.0088x; 1.0088x over previous
//
#include <hip/hip_runtime.h>
#include <math.h>

#define D_MODEL 1024
#define N_HEADS 16
#define HEAD_DIM 64
#define BATCH 2
#define SEQ 2048
#define WIN_L 127
#define WIN_R 128

typedef float f32x4 __attribute__((ext_vector_type(4)));
typedef __bf16 bf16x8 __attribute__((ext_vector_type(8)));
typedef unsigned short ushort8_t __attribute__((ext_vector_type(8)));

typedef const __attribute__((address_space(1))) void* gptr_t;
typedef __attribute__((address_space(3))) void* lptr_t;

__device__ __forceinline__ unsigned short f2bf(float v) {
    unsigned u = __float_as_uint(v);
    unsigned r = (u + 0x7FFF + ((u >> 16) & 1)) >> 16;   // RNE
    return (unsigned short)r;
}

// ---------------------------------------------------------------------------
// fp32 -> bf16 for all three inputs + RoPE cos/sin table, one launch.
// Table: ctab[t*32+f] = (cos(t*invf[f]), sin(t*invf[f])), 2048x32 float2=512KB.
// ---------------------------------------------------------------------------
#define NX_ELEM (4096 * 1024)
#define NW_ELEM (3072 * 1024)
#define NO_ELEM (1024 * 1024)
#define NTOT_ELEM (NX_ELEM + NW_ELEM + NO_ELEM)
#define TAB_ELEM (SEQ * 32)                      // 65536 float2 entries

__global__ __launch_bounds__(256)
void cvt_all(const float* __restrict__ x, const float* __restrict__ wq,
             const float* __restrict__ wo, unsigned short* __restrict__ xb,
             unsigned short* __restrict__ wqb, unsigned short* __restrict__ wob,
             float2* __restrict__ ctab)
{
    int i = (blockIdx.x * 256 + threadIdx.x) * 4;
    if (i < NTOT_ELEM) {
        const float* src;
        unsigned short* dst;
        int off;
        if (i < NX_ELEM)                 { src = x;  dst = xb;  off = i; }
        else if (i < NX_ELEM + NW_ELEM)  { src = wq; dst = wqb; off = i - NX_ELEM; }
        else                             { src = wo; dst = wob; off = i - NX_ELEM - NW_ELEM; }
        float4 f = *(const float4*)(src + off);
        ushort4 o;
        o.x = f2bf(f.x); o.y = f2bf(f.y); o.z = f2bf(f.z); o.w = f2bf(f.w);
        *(ushort4*)(dst + off) = o;
    } else {
        int e0 = i - NTOT_ELEM;                  // 0..TAB_ELEM-4, step 4
#pragma unroll
        for (int e = 0; e < 4; ++e) {
            const int idx = e0 + e;
            const int t = idx >> 5;
            const int f = idx & 31;
            // inv_freq[f] = 10000^(-f/32) = 2^(-f*log2(10000)/32)
            const float invf = exp2f(-(float)f * 0.41524101186092f);
            const float ang = (float)t * invf;
            ctab[idx] = make_float2(cosf(ang), sinf(ang));
        }
    }
}

// ---------------------------------------------------------------------------
// QKV GEMM (NT) with fused RoPE + layout epilogue.  (R7-best config, 164.37us)
// R13: REVERTED R11's swizzle and R12's 2-phase — both measured null-to-
// negative (164.37 -> 164.71 -> 165.77). Session verdict: this 2-barrier
// structure at 3 blocks/CU is at its family ceiling (matches m99/m131-140:
// source-level pipelining/swizzle don't move it; the vmcnt(0)+barrier drain
// is structural and already hidden by cross-block TLP). The 8-phase 256^2
// template doesn't fit (grid would be 192 blocks < 256 CUs; K=1024 too
// short to amortize its prologue).
// ---------------------------------------------------------------------------
__global__ __launch_bounds__(256, 3)
void gemm_qkv(const unsigned short* __restrict__ A,
              const unsigned short* __restrict__ B,
              unsigned short* __restrict__ qb,
              unsigned short* __restrict__ kb,
              unsigned short* __restrict__ vbT,
              const float2* __restrict__ ctab,
              int M, int N, int K)
{
    __shared__ __attribute__((aligned(16))) unsigned short U[17408]; // 34.8 KB
    unsigned short* Al0 = U;             // 128*32
    unsigned short* Bl0 = U + 4096;
    unsigned short* Al1 = U + 8192;
    unsigned short* Bl1 = U + 12288;

    const int tid  = threadIdx.x;
    const int wave = tid >> 6;
    const int lane = tid & 63;
    const int m0 = blockIdx.y * 128;
    const int n0 = blockIdx.x * 128;

    const int wm = (wave >> 1) * 64;
    const int wn = (wave & 1) * 64;
    const int quad = lane >> 4;
    const int l16  = lane & 15;

    const int srow = lane >> 2;          // 0..15
    const int scol = (lane & 3) * 8;     // 0,8,16,24

    f32x4 acc[4][4] = {};

    for (int k0 = 0; k0 < K; k0 += 64) {
        __syncthreads();
#pragma unroll
        for (int l = 0; l < 2; ++l) {
            const int r = l * 64 + wave * 16 + srow;
            const unsigned short* gA = A + (size_t)(m0 + r) * K + k0 + scol;
            const unsigned short* gB = B + (size_t)(n0 + r) * K + k0 + scol;
            __builtin_amdgcn_global_load_lds((gptr_t)gA,        (lptr_t)&Al0[r * 32 + scol], 16, 0, 0);
            __builtin_amdgcn_global_load_lds((gptr_t)gB,        (lptr_t)&Bl0[r * 32 + scol], 16, 0, 0);
            __builtin_amdgcn_global_load_lds((gptr_t)(gA + 32), (lptr_t)&Al1[r * 32 + scol], 16, 0, 0);
            __builtin_amdgcn_global_load_lds((gptr_t)(gB + 32), (lptr_t)&Bl1[r * 32 + scol], 16, 0, 0);
        }
        __syncthreads();

#pragma unroll
        for (int kh = 0; kh < 2; ++kh) {
            const unsigned short* Ap = kh ? Al1 : Al0;
            const unsigned short* Bp = kh ? Bl1 : Bl0;
            bf16x8 af[4], bf[4];
#pragma unroll
            for (int i = 0; i < 4; ++i)
                af[i] = *(const bf16x8*)&Ap[(wm + i * 16 + l16) * 32 + quad * 8];
#pragma unroll
            for (int j = 0; j < 4; ++j)
                bf[j] = *(const bf16x8*)&Bp[(wn + j * 16 + l16) * 32 + quad * 8];
#pragma unroll
            for (int i = 0; i < 4; ++i)
#pragma unroll
                for (int j = 0; j < 4; ++j)
                    acc[i][j] = __builtin_amdgcn_mfma_f32_16x16x32_bf16(af[i], bf[j], acc[i][j], 0, 0, 0);
        }
    }

    __syncthreads();   // all waves done reading staging before Tw overwrites

    // ---- epilogue ----
    const int which = (n0 >> 10);   // 0=q 1=k 2=v, uniform per block
    unsigned short* Tw = U + wave * 4352;   // 64*68 per wave

    if (which != 2) {
#pragma unroll
        for (int i = 0; i < 4; ++i) {
            const int tb = (m0 + wm + i * 16 + quad * 4) & 2047;
#pragma unroll
            for (int jp = 0; jp < 2; ++jp)
#pragma unroll
                for (int r = 0; r < 4; ++r) {
                    const float2 cs = ctab[(tb + r) * 32 + jp * 16 + l16];
                    float x1 = acc[i][jp][r], x2 = acc[i][jp + 2][r];
                    acc[i][jp][r]     = x1 * cs.x - x2 * cs.y;
                    acc[i][jp + 2][r] = x2 * cs.x + x1 * cs.y;
                }
        }
#pragma unroll
        for (int i = 0; i < 4; ++i)
#pragma unroll
            for (int j = 0; j < 4; ++j)
#pragma unroll
                for (int r = 0; r < 4; ++r)
                    Tw[(i * 16 + quad * 4 + r) * 68 + j * 16 + l16] = f2bf(acc[i][j][r]);
    } else {
#pragma unroll
        for (int i = 0; i < 4; ++i)
#pragma unroll
            for (int j = 0; j < 4; ++j) {
                ushort4 pv;
                pv.x = f2bf(acc[i][j][0]); pv.y = f2bf(acc[i][j][1]);
                pv.z = f2bf(acc[i][j][2]); pv.w = f2bf(acc[i][j][3]);
                *(ushort4*)&Tw[(j * 16 + l16) * 68 + i * 16 + quad * 4] = pv;
            }
    }

    {
        const int h   = ((n0 + wn) >> 6) & 15;
        const int nb  = (m0 + wm) >> 11;
        const int tw0 = (m0 + wm) & 2047;
        const int lr8 = lane >> 3;          // 0..7
        const int lc8 = (lane & 7) * 8;     // element offset in row
        if (which != 2) {
            unsigned short* dst = (which == 0 ? qb : kb);
            unsigned short* gb = dst + (((size_t)nb * 16 + h) * SEQ + tw0) * 64;
#pragma unroll
            for (int c = 0; c < 8; ++c) {
                const int row = c * 8 + lr8;
                ushort4 lo = *(const ushort4*)&Tw[row * 68 + lc8];
                ushort4 hi = *(const ushort4*)&Tw[row * 68 + lc8 + 4];
                ushort8_t v8 = {lo.x, lo.y, lo.z, lo.w, hi.x, hi.y, hi.z, hi.w};
                *(ushort8_t*)&gb[row * 64 + lc8] = v8;
            }
        } else {
            unsigned short* gb = vbT + ((size_t)nb * 16 + h) * 64 * SEQ + tw0;
#pragma unroll
            for (int c = 0; c < 8; ++c) {
                const int drow = c * 8 + lr8;
                ushort4 lo = *(const ushort4*)&Tw[drow * 68 + lc8];
                ushort4 hi = *(const ushort4*)&Tw[drow * 68 + lc8 + 4];
                ushort8_t v8 = {lo.x, lo.y, lo.z, lo.w, hi.x, hi.y, hi.z, hi.w};
                *(ushort8_t*)&gb[(size_t)drow * SEQ + lc8] = v8;
            }
        }
    }
}

// ---------------------------------------------------------------------------
// Out-projection GEMM (NT), fp32 out + bias. BM=64/BN=64, 4 blocks/CU (R7).
// ---------------------------------------------------------------------------
__global__ __launch_bounds__(256, 4)
void gemm_out(const unsigned short* __restrict__ A,
              const unsigned short* __restrict__ B,
              const float* __restrict__ bias, float* __restrict__ C,
              int M, int N, int K)
{
    __shared__ __attribute__((aligned(16))) unsigned short Al0[64 * 32];
    __shared__ __attribute__((aligned(16))) unsigned short Al1[64 * 32];
    __shared__ __attribute__((aligned(16))) unsigned short Bl0[64 * 32];
    __shared__ __attribute__((aligned(16))) unsigned short Bl1[64 * 32];

    const int tid  = threadIdx.x;
    const int wave = tid >> 6;
    const int lane = tid & 63;
    const int m0 = blockIdx.y * 64;
    const int n0 = blockIdx.x * 64;

    const int wm = (wave >> 1) * 32;
    const int wn = (wave & 1) * 32;
    const int quad = lane >> 4;
    const int l16  = lane & 15;

    const int srow = lane >> 2;
    const int scol = (lane & 3) * 8;

    f32x4 acc[2][2] = {};

    for (int k0 = 0; k0 < K; k0 += 64) {
        __syncthreads();
        {
            const int r = wave * 16 + srow;        // 0..63
            const unsigned short* gA = A + (size_t)(m0 + r) * K + k0 + scol;
            const unsigned short* gB = B + (size_t)(n0 + r) * K + k0 + scol;
            __builtin_amdgcn_global_load_lds((gptr_t)gA,        (lptr_t)&Al0[r * 32 + scol], 16, 0, 0);
            __builtin_amdgcn_global_load_lds((gptr_t)(gA + 32), (lptr_t)&Al1[r * 32 + scol], 16, 0, 0);
            __builtin_amdgcn_global_load_lds((gptr_t)gB,        (lptr_t)&Bl0[r * 32 + scol], 16, 0, 0);
            __builtin_amdgcn_global_load_lds((gptr_t)(gB + 32), (lptr_t)&Bl1[r * 32 + scol], 16, 0, 0);
        }
        __syncthreads();

#pragma unroll
        for (int kh = 0; kh < 2; ++kh) {
            const unsigned short* Ap = kh ? Al1 : Al0;
            const unsigned short* Bp = kh ? Bl1 : Bl0;
            bf16x8 af[2], bf[2];
#pragma unroll
            for (int i = 0; i < 2; ++i)
                af[i] = *(const bf16x8*)&Ap[(wm + i * 16 + l16) * 32 + quad * 8];
#pragma unroll
            for (int j = 0; j < 2; ++j)
                bf[j] = *(const bf16x8*)&Bp[(wn + j * 16 + l16) * 32 + quad * 8];
#pragma unroll
            for (int i = 0; i < 2; ++i)
#pragma unroll
                for (int j = 0; j < 2; ++j)
                    acc[i][j] = __builtin_amdgcn_mfma_f32_16x16x32_bf16(af[i], bf[j], acc[i][j], 0, 0, 0);
        }
    }

#pragma unroll
    for (int i = 0; i < 2; ++i) {
        const int row_base = m0 + wm + i * 16 + quad * 4;
#pragma unroll
        for (int j = 0; j < 2; ++j) {
            const int col = n0 + wn + j * 16 + l16;
            const float bv = bias[col];
#pragma unroll
            for (int r = 0; r < 4; ++r)
                C[(size_t)(row_base + r) * N + col] = acc[i][j][r] + bv;
        }
    }
}

// ---------------------------------------------------------------------------
// Banded MFMA flash attention — swapped-operand (T12-spirit), P in-register.
// R5 (verified R7/R8/R11/R12, passed): S^T = mfma(K, Q); lane owns P for
// keys 8*quad+{0..7} at its own t = tw+l16 == the PV B-fragment directly.
// V staging kept (R3 lesson: d-major V direct from global is a 64-way
// uncoalesced wave access; LDS staging IS the coalescing conversion).
// ---------------------------------------------------------------------------
__global__ __launch_bounds__(256, 3)
void attn_mfma(const unsigned short* __restrict__ qb,
               const unsigned short* __restrict__ kb,
               const unsigned short* __restrict__ vbT,
               unsigned short* __restrict__ attnb)
{
    __shared__ __attribute__((aligned(16))) unsigned short Vl[64 * 328]; // [d][trel]

    const int tid  = threadIdx.x;
    const int w    = tid >> 6;
    const int lane = tid & 63;
    const int quad = lane >> 4;
    const int l16  = lane & 15;

    const int t0 = blockIdx.x * 64;
    const int h  = blockIdx.y;
    const int nB = blockIdx.z;
    const int nh = nB * 16 + h;

    const int klo_b = max(0, t0 - WIN_L) & ~31;     // block stage origin

    // ---- stage V band via async global->LDS (41 KB, ~10 loads/lane) ----
    {
        const unsigned short* vbase = vbT + (size_t)nh * 64 * SEQ;
#pragma unroll
        for (int k = 0; k < 11; ++k) {
            const int s = k * 256 + tid;            // seg index, 16 B each
            if (s < 64 * 41) {
                const int row = s / 41;
                const int seg = s - row * 41;
                const int tsrc = min(klo_b + seg * 8, SEQ - 8);   // finite clamp
                __builtin_amdgcn_global_load_lds(
                    (gptr_t)(vbase + (size_t)row * SEQ + tsrc),
                    (lptr_t)&Vl[s * 8], 16, 0, 0);
            }
        }
    }
    __syncthreads();   // drains all staging loads

    const int tw  = t0 + w * 16;
    const int klo = max(0, tw - WIN_L) & ~31;
    const int khi = min(SEQ, tw + 16 + WIN_R);          // exclusive
    const int nchunk = (khi - klo + 31) >> 5;           // <= 9

    const int tq = tw + l16;                            // this lane's t (col)

    const unsigned short* qrow = qb + ((size_t)nh * SEQ + tq) * 64;
    bf16x8 aq0 = *(const bf16x8*)(qrow + quad * 8);
    bf16x8 aq1 = *(const bf16x8*)(qrow + 32 + quad * 8);

    const unsigned short* kbase = kb + (size_t)nh * SEQ * 64;

    f32x4 oacc[4] = {};
    float sm = 0.f;

    // prologue: K frags for chunk 0 (even/odd key pairs)
    bf16x8 kA0, kA1, kB0, kB1;
    {
        const int keyA = klo + 2 * l16;
        const unsigned short* kpA = kbase + (size_t)min(keyA, SEQ - 1) * 64;
        const unsigned short* kpB = kbase + (size_t)min(keyA + 1, SEQ - 1) * 64;
        kA0 = *(const bf16x8*)(kpA + quad * 8);
        kA1 = *(const bf16x8*)(kpA + 32 + quad * 8);
        kB0 = *(const bf16x8*)(kpB + quad * 8);
        kB1 = *(const bf16x8*)(kpB + 32 + quad * 8);
    }

    for (int kc = 0; kc < nchunk; ++kc) {
        const int s0 = klo + kc * 32;

        // ---- prefetch chunk kc+1's K frags (in flight through exp/PV) ----
        bf16x8 nA0 = kA0, nA1 = kA1, nB0 = kB0, nB1 = kB1;
        if (kc + 1 < nchunk) {
            const int kyA = s0 + 32 + 2 * l16;
            const unsigned short* kpA = kbase + (size_t)min(kyA, SEQ - 1) * 64;
            const unsigned short* kpB = kbase + (size_t)min(kyA + 1, SEQ - 1) * 64;
            nA0 = *(const bf16x8*)(kpA + quad * 8);
            nA1 = *(const bf16x8*)(kpA + 32 + quad * 8);
            nB0 = *(const bf16x8*)(kpB + quad * 8);
            nB1 = *(const bf16x8*)(kpB + 32 + quad * 8);
        }

        // ---- QK^T swapped: S^T tiles (A = K, B = Q) ----
        f32x4 sa = {0.f, 0.f, 0.f, 0.f};   // even keys: s0 + 8*quad + 2r
        f32x4 sb = {0.f, 0.f, 0.f, 0.f};   // odd  keys: s0 + 8*quad + 2r + 1
        __builtin_amdgcn_s_setprio(1);
        sa = __builtin_amdgcn_mfma_f32_16x16x32_bf16(kA0, aq0, sa, 0, 0, 0);
        sa = __builtin_amdgcn_mfma_f32_16x16x32_bf16(kA1, aq1, sa, 0, 0, 0);
        sb = __builtin_amdgcn_mfma_f32_16x16x32_bf16(kB0, aq0, sb, 0, 0, 0);
        sb = __builtin_amdgcn_mfma_f32_16x16x32_bf16(kB1, aq1, sb, 0, 0, 0);
        __builtin_amdgcn_s_setprio(0);

        // ---- mask + exp + row-sum; P stays in registers ----
        ushort8_t pk;
#pragma unroll
        for (int r = 0; r < 4; ++r) {
            const int ka = s0 + 8 * quad + 2 * r;
            const int kb2 = ka + 1;
            const bool vA = (ka  < khi) && (ka  >= tq - WIN_L) && (ka  <= tq + WIN_R);
            const bool vB = (kb2 < khi) && (kb2 >= tq - WIN_L) && (kb2 <= tq + WIN_R);
            // exp(s/8) = exp2(s * 0.125*log2(e)); folded constant (1 mul)
            float p0 = vA ? exp2f(sa[r] * 0.18033688011f) : 0.f;
            float p1 = vB ? exp2f(sb[r] * 0.18033688011f) : 0.f;
            sm += p0 + p1;
            pk[2 * r]     = f2bf(p0);
            pk[2 * r + 1] = f2bf(p1);
        }
        bf16x8 pf = *(bf16x8*)&pk;   // B-frag: keys 8*quad+0..7, col = tq

        // ---- PV swapped: O^T += mfma(A = V^T from LDS, B = P^T in-reg) ----
        const int rel = s0 - klo_b + quad * 8;
        __builtin_amdgcn_s_setprio(1);
#pragma unroll
        for (int j = 0; j < 4; ++j) {
            bf16x8 vf = *(const bf16x8*)&Vl[(j * 16 + l16) * 328 + rel];
            oacc[j] = __builtin_amdgcn_mfma_f32_16x16x32_bf16(vf, pf, oacc[j], 0, 0, 0);
        }
        __builtin_amdgcn_s_setprio(0);

        kA0 = nA0; kA1 = nA1; kB0 = nB0; kB1 = nB1;
    }

    // ---- normalize: lanes sharing t = l16 are the 4 quads (xor 16, 32) ----
    sm += __shfl_xor(sm, 16, 64);
    sm += __shfl_xor(sm, 32, 64);
    const float inv = 1.0f / sm;

    // ---- store O^T: lane holds d = j*16 + quad*4 + r at row t = tq ----
    unsigned short* orow = attnb + ((size_t)(nB * SEQ + tq)) * D_MODEL + h * 64;
#pragma unroll
    for (int j = 0; j < 4; ++j) {
        ushort4 o4;
        o4.x = f2bf(oacc[j][0] * inv);
        o4.y = f2bf(oacc[j][1] * inv);
        o4.z = f2bf(oacc[j][2] * inv);
        o4.w = f2bf(oacc[j][3] * inv);
        *(ushort4*)&orow[j * 16 + quad * 4] = o4;
    }
}

// ---------------------------------------------------------------------------
extern "C" void kernel_launch(void* const* d_in, const int* in_sizes, int n_in,
                              void* d_out, int out_size, void* d_ws, size_t ws_size,
                              hipStream_t stream)
{
    (void)in_sizes; (void)n_in; (void)out_size; (void)ws_size;
    const float* x     = (const float*)d_in[0];
    const float* w_qkv = (const float*)d_in[1];
    const float* w_out = (const float*)d_in[2];
    const float* b_out = (const float*)d_in[3];
    float* out = (float*)d_out;

    const int M = BATCH * SEQ;                 // 4096

    // ws layout (ushorts), ~42.5 MB total:
    //   qb | kb | vbT | wob | xb | wqb | ctab   (attnb reuses xb after QKV)
    unsigned short* qb  = (unsigned short*)d_ws;
    unsigned short* kb  = qb  + (size_t)4194304;
    unsigned short* vbT = kb  + (size_t)4194304;
    unsigned short* wob = vbT + (size_t)4194304;
    unsigned short* xb  = wob + (size_t)1048576;
    unsigned short* wqb = xb  + (size_t)4194304;
    float2* ctab = (float2*)(wqb + (size_t)4194304);   // 512 KB
    unsigned short* attnb = xb;

    dim3 blk(256);

    // 0) fp32 -> bf16 conversions + RoPE table (single launch)
    cvt_all<<<dim3((NTOT_ELEM + TAB_ELEM * 4) / 4 / 256), blk, 0, stream>>>(
        x, w_qkv, w_out, xb, wqb, wob, ctab);

    // 1) fused QKV projection + RoPE -> qb,kb [n,h,t,64], vbT [n,h,64,t] (bf16)
    gemm_qkv<<<dim3(3 * D_MODEL / 128, M / 128), blk, 0, stream>>>(
        xb, wqb, qb, kb, vbT, ctab, M, 3 * D_MODEL, D_MODEL);

    // 2) banded MFMA attention (swapped-operand, P in-register) -> attnb
    attn_mfma<<<dim3(SEQ / 64, N_HEADS, BATCH), blk, 0, stream>>>(qb, kb, vbT, attnb);

    // 3) out = attn @ w_out^T + b_out   (BM=64/BN=64: grid 16 x 64 = 1024 blocks)
    gemm_out<<<dim3(D_MODEL / 64, M / 64), blk, 0, stream>>>(
        attnb, wob, b_out, out, M, D_MODEL, D_MODEL);
}

// Round 16
// 158.243 us; speedup vs baseline: 1.0476x; 1.0384x over previous
//
#include <hip/hip_runtime.h>
#include <math.h>

#define D_MODEL 1024
#define N_HEADS 16
#define HEAD_DIM 64
#define BATCH 2
#define SEQ 2048
#define WIN_L 127
#define WIN_R 128

typedef float f32x4 __attribute__((ext_vector_type(4)));
typedef __bf16 bf16x8 __attribute__((ext_vector_type(8)));
typedef unsigned short ushort8_t __attribute__((ext_vector_type(8)));

typedef const __attribute__((address_space(1))) void* gptr_t;
typedef __attribute__((address_space(3))) void* lptr_t;

__device__ __forceinline__ unsigned short f2bf(float v) {
    unsigned u = __float_as_uint(v);
    unsigned r = (u + 0x7FFF + ((u >> 16) & 1)) >> 16;   // RNE
    return (unsigned short)r;
}

// ---------------------------------------------------------------------------
// fp32 -> bf16 for all three inputs + RoPE cos/sin table, one launch.
// Table: ctab[t*32+f] = (cos(t*invf[f]), sin(t*invf[f])), 2048x32 float2=512KB.
// ---------------------------------------------------------------------------
#define NX_ELEM (4096 * 1024)
#define NW_ELEM (3072 * 1024)
#define NO_ELEM (1024 * 1024)
#define NTOT_ELEM (NX_ELEM + NW_ELEM + NO_ELEM)
#define TAB_ELEM (SEQ * 32)                      // 65536 float2 entries

__global__ __launch_bounds__(256)
void cvt_all(const float* __restrict__ x, const float* __restrict__ wq,
             const float* __restrict__ wo, unsigned short* __restrict__ xb,
             unsigned short* __restrict__ wqb, unsigned short* __restrict__ wob,
             float2* __restrict__ ctab)
{
    int i = (blockIdx.x * 256 + threadIdx.x) * 4;
    if (i < NTOT_ELEM) {
        const float* src;
        unsigned short* dst;
        int off;
        if (i < NX_ELEM)                 { src = x;  dst = xb;  off = i; }
        else if (i < NX_ELEM + NW_ELEM)  { src = wq; dst = wqb; off = i - NX_ELEM; }
        else                             { src = wo; dst = wob; off = i - NX_ELEM - NW_ELEM; }
        float4 f = *(const float4*)(src + off);
        ushort4 o;
        o.x = f2bf(f.x); o.y = f2bf(f.y); o.z = f2bf(f.z); o.w = f2bf(f.w);
        *(ushort4*)(dst + off) = o;
    } else {
        int e0 = i - NTOT_ELEM;                  // 0..TAB_ELEM-4, step 4
#pragma unroll
        for (int e = 0; e < 4; ++e) {
            const int idx = e0 + e;
            const int t = idx >> 5;
            const int f = idx & 31;
            // inv_freq[f] = 10000^(-f/32) = 2^(-f*log2(10000)/32)
            const float invf = exp2f(-(float)f * 0.41524101186092f);
            const float ang = (float)t * invf;
            ctab[idx] = make_float2(cosf(ang), sinf(ang));
        }
    }
}

// ---------------------------------------------------------------------------
// QKV GEMM (NT) with fused RoPE + layout epilogue.  (R7-best config, 164.37us)
// Session verdict (R8/R11/R12): occupancy cap, LDS swizzle, and 2-phase
// pipelining all null-to-negative on this 2-barrier structure at 3 blocks/CU
// — its family ceiling (matches m99/m131-140). Kept at best-measured config.
// ---------------------------------------------------------------------------
__global__ __launch_bounds__(256, 3)
void gemm_qkv(const unsigned short* __restrict__ A,
              const unsigned short* __restrict__ B,
              unsigned short* __restrict__ qb,
              unsigned short* __restrict__ kb,
              unsigned short* __restrict__ vbT,
              const float2* __restrict__ ctab,
              int M, int N, int K)
{
    __shared__ __attribute__((aligned(16))) unsigned short U[17408]; // 34.8 KB
    unsigned short* Al0 = U;             // 128*32
    unsigned short* Bl0 = U + 4096;
    unsigned short* Al1 = U + 8192;
    unsigned short* Bl1 = U + 12288;

    const int tid  = threadIdx.x;
    const int wave = tid >> 6;
    const int lane = tid & 63;
    const int m0 = blockIdx.y * 128;
    const int n0 = blockIdx.x * 128;

    const int wm = (wave >> 1) * 64;
    const int wn = (wave & 1) * 64;
    const int quad = lane >> 4;
    const int l16  = lane & 15;

    const int srow = lane >> 2;          // 0..15
    const int scol = (lane & 3) * 8;     // 0,8,16,24

    f32x4 acc[4][4] = {};

    for (int k0 = 0; k0 < K; k0 += 64) {
        __syncthreads();
#pragma unroll
        for (int l = 0; l < 2; ++l) {
            const int r = l * 64 + wave * 16 + srow;
            const unsigned short* gA = A + (size_t)(m0 + r) * K + k0 + scol;
            const unsigned short* gB = B + (size_t)(n0 + r) * K + k0 + scol;
            __builtin_amdgcn_global_load_lds((gptr_t)gA,        (lptr_t)&Al0[r * 32 + scol], 16, 0, 0);
            __builtin_amdgcn_global_load_lds((gptr_t)gB,        (lptr_t)&Bl0[r * 32 + scol], 16, 0, 0);
            __builtin_amdgcn_global_load_lds((gptr_t)(gA + 32), (lptr_t)&Al1[r * 32 + scol], 16, 0, 0);
            __builtin_amdgcn_global_load_lds((gptr_t)(gB + 32), (lptr_t)&Bl1[r * 32 + scol], 16, 0, 0);
        }
        __syncthreads();

#pragma unroll
        for (int kh = 0; kh < 2; ++kh) {
            const unsigned short* Ap = kh ? Al1 : Al0;
            const unsigned short* Bp = kh ? Bl1 : Bl0;
            bf16x8 af[4], bf[4];
#pragma unroll
            for (int i = 0; i < 4; ++i)
                af[i] = *(const bf16x8*)&Ap[(wm + i * 16 + l16) * 32 + quad * 8];
#pragma unroll
            for (int j = 0; j < 4; ++j)
                bf[j] = *(const bf16x8*)&Bp[(wn + j * 16 + l16) * 32 + quad * 8];
#pragma unroll
            for (int i = 0; i < 4; ++i)
#pragma unroll
                for (int j = 0; j < 4; ++j)
                    acc[i][j] = __builtin_amdgcn_mfma_f32_16x16x32_bf16(af[i], bf[j], acc[i][j], 0, 0, 0);
        }
    }

    __syncthreads();   // all waves done reading staging before Tw overwrites

    // ---- epilogue ----
    const int which = (n0 >> 10);   // 0=q 1=k 2=v, uniform per block
    unsigned short* Tw = U + wave * 4352;   // 64*68 per wave

    if (which != 2) {
#pragma unroll
        for (int i = 0; i < 4; ++i) {
            const int tb = (m0 + wm + i * 16 + quad * 4) & 2047;
#pragma unroll
            for (int jp = 0; jp < 2; ++jp)
#pragma unroll
                for (int r = 0; r < 4; ++r) {
                    const float2 cs = ctab[(tb + r) * 32 + jp * 16 + l16];
                    float x1 = acc[i][jp][r], x2 = acc[i][jp + 2][r];
                    acc[i][jp][r]     = x1 * cs.x - x2 * cs.y;
                    acc[i][jp + 2][r] = x2 * cs.x + x1 * cs.y;
                }
        }
#pragma unroll
        for (int i = 0; i < 4; ++i)
#pragma unroll
            for (int j = 0; j < 4; ++j)
#pragma unroll
                for (int r = 0; r < 4; ++r)
                    Tw[(i * 16 + quad * 4 + r) * 68 + j * 16 + l16] = f2bf(acc[i][j][r]);
    } else {
#pragma unroll
        for (int i = 0; i < 4; ++i)
#pragma unroll
            for (int j = 0; j < 4; ++j) {
                ushort4 pv;
                pv.x = f2bf(acc[i][j][0]); pv.y = f2bf(acc[i][j][1]);
                pv.z = f2bf(acc[i][j][2]); pv.w = f2bf(acc[i][j][3]);
                *(ushort4*)&Tw[(j * 16 + l16) * 68 + i * 16 + quad * 4] = pv;
            }
    }

    {
        const int h   = ((n0 + wn) >> 6) & 15;
        const int nb  = (m0 + wm) >> 11;
        const int tw0 = (m0 + wm) & 2047;
        const int lr8 = lane >> 3;          // 0..7
        const int lc8 = (lane & 7) * 8;     // element offset in row
        if (which != 2) {
            unsigned short* dst = (which == 0 ? qb : kb);
            unsigned short* gb = dst + (((size_t)nb * 16 + h) * SEQ + tw0) * 64;
#pragma unroll
            for (int c = 0; c < 8; ++c) {
                const int row = c * 8 + lr8;
                ushort4 lo = *(const ushort4*)&Tw[row * 68 + lc8];
                ushort4 hi = *(const ushort4*)&Tw[row * 68 + lc8 + 4];
                ushort8_t v8 = {lo.x, lo.y, lo.z, lo.w, hi.x, hi.y, hi.z, hi.w};
                *(ushort8_t*)&gb[row * 64 + lc8] = v8;
            }
        } else {
            unsigned short* gb = vbT + ((size_t)nb * 16 + h) * 64 * SEQ + tw0;
#pragma unroll
            for (int c = 0; c < 8; ++c) {
                const int drow = c * 8 + lr8;
                ushort4 lo = *(const ushort4*)&Tw[drow * 68 + lc8];
                ushort4 hi = *(const ushort4*)&Tw[drow * 68 + lc8 + 4];
                ushort8_t v8 = {lo.x, lo.y, lo.z, lo.w, hi.x, hi.y, hi.z, hi.w};
                *(ushort8_t*)&gb[(size_t)drow * SEQ + lc8] = v8;
            }
        }
    }
}

// ---------------------------------------------------------------------------
// Out-projection GEMM (NT), fp32 out + bias. BM=64/BN=64, 4 blocks/CU (R7).
// ---------------------------------------------------------------------------
__global__ __launch_bounds__(256, 4)
void gemm_out(const unsigned short* __restrict__ A,
              const unsigned short* __restrict__ B,
              const float* __restrict__ bias, float* __restrict__ C,
              int M, int N, int K)
{
    __shared__ __attribute__((aligned(16))) unsigned short Al0[64 * 32];
    __shared__ __attribute__((aligned(16))) unsigned short Al1[64 * 32];
    __shared__ __attribute__((aligned(16))) unsigned short Bl0[64 * 32];
    __shared__ __attribute__((aligned(16))) unsigned short Bl1[64 * 32];

    const int tid  = threadIdx.x;
    const int wave = tid >> 6;
    const int lane = tid & 63;
    const int m0 = blockIdx.y * 64;
    const int n0 = blockIdx.x * 64;

    const int wm = (wave >> 1) * 32;
    const int wn = (wave & 1) * 32;
    const int quad = lane >> 4;
    const int l16  = lane & 15;

    const int srow = lane >> 2;
    const int scol = (lane & 3) * 8;

    f32x4 acc[2][2] = {};

    for (int k0 = 0; k0 < K; k0 += 64) {
        __syncthreads();
        {
            const int r = wave * 16 + srow;        // 0..63
            const unsigned short* gA = A + (size_t)(m0 + r) * K + k0 + scol;
            const unsigned short* gB = B + (size_t)(n0 + r) * K + k0 + scol;
            __builtin_amdgcn_global_load_lds((gptr_t)gA,        (lptr_t)&Al0[r * 32 + scol], 16, 0, 0);
            __builtin_amdgcn_global_load_lds((gptr_t)(gA + 32), (lptr_t)&Al1[r * 32 + scol], 16, 0, 0);
            __builtin_amdgcn_global_load_lds((gptr_t)gB,        (lptr_t)&Bl0[r * 32 + scol], 16, 0, 0);
            __builtin_amdgcn_global_load_lds((gptr_t)(gB + 32), (lptr_t)&Bl1[r * 32 + scol], 16, 0, 0);
        }
        __syncthreads();

#pragma unroll
        for (int kh = 0; kh < 2; ++kh) {
            const unsigned short* Ap = kh ? Al1 : Al0;
            const unsigned short* Bp = kh ? Bl1 : Bl0;
            bf16x8 af[2], bf[2];
#pragma unroll
            for (int i = 0; i < 2; ++i)
                af[i] = *(const bf16x8*)&Ap[(wm + i * 16 + l16) * 32 + quad * 8];
#pragma unroll
            for (int j = 0; j < 2; ++j)
                bf[j] = *(const bf16x8*)&Bp[(wn + j * 16 + l16) * 32 + quad * 8];
#pragma unroll
            for (int i = 0; i < 2; ++i)
#pragma unroll
                for (int j = 0; j < 2; ++j)
                    acc[i][j] = __builtin_amdgcn_mfma_f32_16x16x32_bf16(af[i], bf[j], acc[i][j], 0, 0, 0);
        }
    }

#pragma unroll
    for (int i = 0; i < 2; ++i) {
        const int row_base = m0 + wm + i * 16 + quad * 4;
#pragma unroll
        for (int j = 0; j < 2; ++j) {
            const int col = n0 + wn + j * 16 + l16;
            const float bv = bias[col];
#pragma unroll
            for (int r = 0; r < 4; ++r)
                C[(size_t)(row_base + r) * N + col] = acc[i][j][r] + bv;
        }
    }
}

// ---------------------------------------------------------------------------
// Banded MFMA flash attention — swapped-operand, P in-register (R5-verified).
// R15: 128-row blocks (8 waves, 512 threads), shared V-band in LDS.
// Rationale: attn MFMA floor ~2.4us, BW floor ~10-15us, measured ~35-40us ->
// latency-bound at 12 waves/CU (3 blocks x 41KB Vl, 37.5% occupancy).
// Merging two 64-row tiles shares their 94%-overlapping V-bands: span 384
// -> pitch 49*8=392 (odd multiple of 8 ushorts => 16 V-read lanes spread
// over 8 16B-slot classes, 2-way = free, same as old 41*8). LDS 49KB ->
// 2 blocks/CU at VGPR<=128 = 16 waves/CU (+33%), grid 512 = exactly one
// residency generation, stage traffic/row -40%. Per-wave inner loop is
// bit-identical (rel_max=383<392 verified for all t0/w incl. edges).
// ---------------------------------------------------------------------------
#define VPITCH 392          // 49*8 ushorts; odd seg count => conflict-free
#define VSEGS  (64 * 49)    // 3136 16B segments

__global__ __launch_bounds__(512, 4)
void attn_mfma(const unsigned short* __restrict__ qb,
               const unsigned short* __restrict__ kb,
               const unsigned short* __restrict__ vbT,
               unsigned short* __restrict__ attnb)
{
    __shared__ __attribute__((aligned(16))) unsigned short Vl[64 * VPITCH]; // 49 KB

    const int tid  = threadIdx.x;
    const int w    = tid >> 6;          // 0..7
    const int lane = tid & 63;
    const int quad = lane >> 4;
    const int l16  = lane & 15;

    const int t0 = blockIdx.x * 128;
    const int h  = blockIdx.y;
    const int nB = blockIdx.z;
    const int nh = nB * 16 + h;

    const int klo_b = max(0, t0 - WIN_L) & ~31;     // block stage origin

    // ---- stage V band via async global->LDS (49 KB, 3136 segs, 512 thr) ----
    {
        const unsigned short* vbase = vbT + (size_t)nh * 64 * SEQ;
#pragma unroll
        for (int k = 0; k < 7; ++k) {
            const int s = k * 512 + tid;            // seg index, 16 B each
            if (s < VSEGS) {
                const int row = s / 49;
                const int seg = s - row * 49;
                const int tsrc = min(klo_b + seg * 8, SEQ - 8);   // finite clamp
                __builtin_amdgcn_global_load_lds(
                    (gptr_t)(vbase + (size_t)row * SEQ + tsrc),
                    (lptr_t)&Vl[(row * 49 + seg) * 8], 16, 0, 0);
            }
        }
    }
    __syncthreads();   // drains all staging loads

    const int tw  = t0 + w * 16;
    const int klo = max(0, tw - WIN_L) & ~31;
    const int khi = min(SEQ, tw + 16 + WIN_R);          // exclusive
    const int nchunk = (khi - klo + 31) >> 5;           // <= 9

    const int tq = tw + l16;                            // this lane's t (col)

    const unsigned short* qrow = qb + ((size_t)nh * SEQ + tq) * 64;
    bf16x8 aq0 = *(const bf16x8*)(qrow + quad * 8);
    bf16x8 aq1 = *(const bf16x8*)(qrow + 32 + quad * 8);

    const unsigned short* kbase = kb + (size_t)nh * SEQ * 64;

    f32x4 oacc[4] = {};
    float sm = 0.f;

    // prologue: K frags for chunk 0 (even/odd key pairs)
    bf16x8 kA0, kA1, kB0, kB1;
    {
        const int keyA = klo + 2 * l16;
        const unsigned short* kpA = kbase + (size_t)min(keyA, SEQ - 1) * 64;
        const unsigned short* kpB = kbase + (size_t)min(keyA + 1, SEQ - 1) * 64;
        kA0 = *(const bf16x8*)(kpA + quad * 8);
        kA1 = *(const bf16x8*)(kpA + 32 + quad * 8);
        kB0 = *(const bf16x8*)(kpB + quad * 8);
        kB1 = *(const bf16x8*)(kpB + 32 + quad * 8);
    }

    for (int kc = 0; kc < nchunk; ++kc) {
        const int s0 = klo + kc * 32;

        // ---- prefetch chunk kc+1's K frags (in flight through exp/PV) ----
        bf16x8 nA0 = kA0, nA1 = kA1, nB0 = kB0, nB1 = kB1;
        if (kc + 1 < nchunk) {
            const int kyA = s0 + 32 + 2 * l16;
            const unsigned short* kpA = kbase + (size_t)min(kyA, SEQ - 1) * 64;
            const unsigned short* kpB = kbase + (size_t)min(kyA + 1, SEQ - 1) * 64;
            nA0 = *(const bf16x8*)(kpA + quad * 8);
            nA1 = *(const bf16x8*)(kpA + 32 + quad * 8);
            nB0 = *(const bf16x8*)(kpB + quad * 8);
            nB1 = *(const bf16x8*)(kpB + 32 + quad * 8);
        }

        // ---- QK^T swapped: S^T tiles (A = K, B = Q) ----
        f32x4 sa = {0.f, 0.f, 0.f, 0.f};   // even keys: s0 + 8*quad + 2r
        f32x4 sb = {0.f, 0.f, 0.f, 0.f};   // odd  keys: s0 + 8*quad + 2r + 1
        __builtin_amdgcn_s_setprio(1);
        sa = __builtin_amdgcn_mfma_f32_16x16x32_bf16(kA0, aq0, sa, 0, 0, 0);
        sa = __builtin_amdgcn_mfma_f32_16x16x32_bf16(kA1, aq1, sa, 0, 0, 0);
        sb = __builtin_amdgcn_mfma_f32_16x16x32_bf16(kB0, aq0, sb, 0, 0, 0);
        sb = __builtin_amdgcn_mfma_f32_16x16x32_bf16(kB1, aq1, sb, 0, 0, 0);
        __builtin_amdgcn_s_setprio(0);

        // ---- mask + exp + row-sum; P stays in registers ----
        ushort8_t pk;
#pragma unroll
        for (int r = 0; r < 4; ++r) {
            const int ka = s0 + 8 * quad + 2 * r;
            const int kb2 = ka + 1;
            const bool vA = (ka  < khi) && (ka  >= tq - WIN_L) && (ka  <= tq + WIN_R);
            const bool vB = (kb2 < khi) && (kb2 >= tq - WIN_L) && (kb2 <= tq + WIN_R);
            // exp(s/8) = exp2(s * 0.125*log2(e)); folded constant (1 mul)
            float p0 = vA ? exp2f(sa[r] * 0.18033688011f) : 0.f;
            float p1 = vB ? exp2f(sb[r] * 0.18033688011f) : 0.f;
            sm += p0 + p1;
            pk[2 * r]     = f2bf(p0);
            pk[2 * r + 1] = f2bf(p1);
        }
        bf16x8 pf = *(bf16x8*)&pk;   // B-frag: keys 8*quad+0..7, col = tq

        // ---- PV swapped: O^T += mfma(A = V^T from LDS, B = P^T in-reg) ----
        const int rel = s0 - klo_b + quad * 8;
        __builtin_amdgcn_s_setprio(1);
#pragma unroll
        for (int j = 0; j < 4; ++j) {
            bf16x8 vf = *(const bf16x8*)&Vl[(j * 16 + l16) * VPITCH + rel];
            oacc[j] = __builtin_amdgcn_mfma_f32_16x16x32_bf16(vf, pf, oacc[j], 0, 0, 0);
        }
        __builtin_amdgcn_s_setprio(0);

        kA0 = nA0; kA1 = nA1; kB0 = nB0; kB1 = nB1;
    }

    // ---- normalize: lanes sharing t = l16 are the 4 quads (xor 16, 32) ----
    sm += __shfl_xor(sm, 16, 64);
    sm += __shfl_xor(sm, 32, 64);
    const float inv = 1.0f / sm;

    // ---- store O^T: lane holds d = j*16 + quad*4 + r at row t = tq ----
    unsigned short* orow = attnb + ((size_t)(nB * SEQ + tq)) * D_MODEL + h * 64;
#pragma unroll
    for (int j = 0; j < 4; ++j) {
        ushort4 o4;
        o4.x = f2bf(oacc[j][0] * inv);
        o4.y = f2bf(oacc[j][1] * inv);
        o4.z = f2bf(oacc[j][2] * inv);
        o4.w = f2bf(oacc[j][3] * inv);
        *(ushort4*)&orow[j * 16 + quad * 4] = o4;
    }
}

// ---------------------------------------------------------------------------
extern "C" void kernel_launch(void* const* d_in, const int* in_sizes, int n_in,
                              void* d_out, int out_size, void* d_ws, size_t ws_size,
                              hipStream_t stream)
{
    (void)in_sizes; (void)n_in; (void)out_size; (void)ws_size;
    const float* x     = (const float*)d_in[0];
    const float* w_qkv = (const float*)d_in[1];
    const float* w_out = (const float*)d_in[2];
    const float* b_out = (const float*)d_in[3];
    float* out = (float*)d_out;

    const int M = BATCH * SEQ;                 // 4096

    // ws layout (ushorts), ~42.5 MB total:
    //   qb | kb | vbT | wob | xb | wqb | ctab   (attnb reuses xb after QKV)
    unsigned short* qb  = (unsigned short*)d_ws;
    unsigned short* kb  = qb  + (size_t)4194304;
    unsigned short* vbT = kb  + (size_t)4194304;
    unsigned short* wob = vbT + (size_t)4194304;
    unsigned short* xb  = wob + (size_t)1048576;
    unsigned short* wqb = xb  + (size_t)4194304;
    float2* ctab = (float2*)(wqb + (size_t)4194304);   // 512 KB
    unsigned short* attnb = xb;

    dim3 blk(256);

    // 0) fp32 -> bf16 conversions + RoPE table (single launch)
    cvt_all<<<dim3((NTOT_ELEM + TAB_ELEM * 4) / 4 / 256), blk, 0, stream>>>(
        x, w_qkv, w_out, xb, wqb, wob, ctab);

    // 1) fused QKV projection + RoPE -> qb,kb [n,h,t,64], vbT [n,h,64,t] (bf16)
    gemm_qkv<<<dim3(3 * D_MODEL / 128, M / 128), blk, 0, stream>>>(
        xb, wqb, qb, kb, vbT, ctab, M, 3 * D_MODEL, D_MODEL);

    // 2) banded MFMA attention: 128-row blocks, 8 waves, shared V-band
    attn_mfma<<<dim3(SEQ / 128, N_HEADS, BATCH), dim3(512), 0, stream>>>(
        qb, kb, vbT, attnb);

    // 3) out = attn @ w_out^T + b_out   (BM=64/BN=64: grid 16 x 64 = 1024 blocks)
    gemm_out<<<dim3(D_MODEL / 64, M / 64), blk, 0, stream>>>(
        attnb, wob, b_out, out, M, D_MODEL, D_MODEL);
}